// Round 10
// baseline (62.982 us; speedup 1.0000x reference)
//
#include <hip/hip_runtime.h>

typedef float f4 __attribute__((ext_vector_type(4)));

#define TT 4096
#define CC 128
#define BB 32
#define C4 (CC / 4)        // 32 float4 per row
#define NGM 16             // moment slabs per batch (256 rows each)
#define SLAB (TT / NGM)    // 256
#define NTILE 64           // emit tiles per batch (64 rows each)

// ---------------------------------------------------------------------------
// Kernel 1 (split grid), PLAIN stores:
//   blocks [0, 512):     partial moments over a 256-row slab per (b, slab).
//   blocks [512, 2560):  zero-fill of output planes 2 and 3.
// partial layout: [b*NGM+s][3][C4] float4.
// ---------------------------------------------------------------------------
__global__ __launch_bounds__(256) void k_moments_zero(const f4* __restrict__ x4,
                                                      f4* __restrict__ partial,
                                                      f4* __restrict__ out,
                                                      float scale) {
    const size_t N4 = (size_t)BB * TT * C4;
    const int blk = blockIdx.x;
    const int tid = threadIdx.x;
    const int r = tid >> 5;    // 0..7
    const int q = tid & 31;    // 0..31

    if (blk < BB * NGM) {
        const int b = blk >> 4;
        const int s = blk & 15;
        const f4* xb = x4 + (size_t)b * TT * C4;
        const int t0 = s * SLAB;
        f4 m0 = (f4)0.0f, m1 = (f4)0.0f, m2 = (f4)0.0f;
#pragma unroll 8
        for (int k = 0; k < SLAB / 8; ++k) {   // 32 iterations
            const int t = t0 + r + (k << 3);
            const float u = fmaf((float)t, scale, -0.5f);
            const f4 v = xb[(size_t)t * C4 + q];
            m0 += v;
            m1 += u * v;
            m2 += (u * u) * v;
        }
        __shared__ f4 red[3][8][32];
        red[0][r][q] = m0;
        red[1][r][q] = m1;
        red[2][r][q] = m2;
        __syncthreads();
        if (tid < 32) {
#pragma unroll
            for (int j = 0; j < 3; ++j) {
                f4 acc = red[j][0][tid];
#pragma unroll
                for (int rr = 1; rr < 8; ++rr) acc += red[j][rr][tid];
                partial[(size_t)blk * (3 * C4) + j * C4 + tid] = acc;
            }
        }
    } else {
        // zero-fill planes 2 and 3, one 64-row tile per block — PLAIN stores
        const int zid = blk - BB * NGM;
        const int b = zid >> 6;
        const int tile = zid & 63;
        const size_t base = (size_t)b * TT * C4 + (size_t)(tile * 64) * C4;
        const f4 z = (f4)0.0f;
#pragma unroll
        for (int k = 0; k < 8; ++k) {
            const size_t idx = base + (size_t)(r + (k << 3)) * C4 + q;
            out[2 * N4 + idx] = z;
            out[3 * N4 + idx] = z;
        }
    }
}

// ---------------------------------------------------------------------------
// Kernel 2: reduce 16 partial records to coefficients, emit low/res for a
// 64-row tile. PLAIN stores (A/B vs nontemporal — R9 post-mortem).
// ---------------------------------------------------------------------------
__global__ __launch_bounds__(256) void k_emit(const f4* __restrict__ x4,
                                              const f4* __restrict__ partial,
                                              f4* __restrict__ out,
                                              float scale, float c20,
                                              float invS0, float invS2,
                                              float invD) {
    const size_t N4 = (size_t)BB * TT * C4;
    const int blk = blockIdx.x;
    const int b = blk >> 6;
    const int tile = blk & 63;
    const int tid = threadIdx.x;
    const int r = tid >> 5;
    const int q = tid & 31;

    __shared__ f4 red[3][8][32];
    __shared__ f4 ca[3][32];

    // Phase A: reduce 16 partial records of batch b (L2-resident).
    const f4* pb = partial + (size_t)b * (NGM * 3 * C4);
#pragma unroll
    for (int j = 0; j < 3; ++j) {
        const f4 e0 = pb[(size_t)(2 * r + 0) * (3 * C4) + j * C4 + q];
        const f4 e1 = pb[(size_t)(2 * r + 1) * (3 * C4) + j * C4 + q];
        red[j][r][q] = e0 + e1;
    }
    __syncthreads();
    if (tid < 32) {
        f4 s0 = (f4)0.0f, s1 = (f4)0.0f, s2 = (f4)0.0f;
#pragma unroll
        for (int rr = 0; rr < 8; ++rr) {
            s0 += red[0][rr][tid];
            s1 += red[1][rr][tid];
            s2 += red[2][rr][tid];
        }
        ca[0][tid] = s0 * invS0;
        ca[1][tid] = s1 * invS2;
        ca[2][tid] = (s2 - c20 * s0) * invD;
    }
    __syncthreads();

    const f4 a0 = ca[0][q];
    const f4 a1 = ca[1][q];
    const f4 a2 = ca[2][q];

    // Phase B: emit low/res for 64 rows (x re-read is L3-hot from k1).
    const size_t base = (size_t)b * TT * C4;
    const int t0 = tile * 64;
#pragma unroll
    for (int k = 0; k < 8; ++k) {
        const int t = t0 + r + (k << 3);
        const float u = fmaf((float)t, scale, -0.5f);
        const float w = fmaf(u, u, -c20);
        const size_t idx = base + (size_t)t * C4 + q;
        const f4 xv = x4[idx];
        const f4 lo = a0 + u * a1 + w * a2;
        const f4 re = xv - lo;
        out[idx] = lo;
        out[N4 + idx] = re;
    }
}

// ---------------------------------------------------------------------------
extern "C" void kernel_launch(void* const* d_in, const int* in_sizes, int n_in,
                              void* d_out, int out_size, void* d_ws, size_t ws_size,
                              hipStream_t stream) {
    const float* x = (const float*)d_in[0];
    float* out = (float*)d_out;
    const size_t N = (size_t)BB * TT * CC;   // elems per plane

    // Exact basis scalars in double on host (t symmetric => S1 = S3 = 0).
    double S0 = (double)TT, S2 = 0.0, S4 = 0.0;
    for (int i = 0; i < TT; ++i) {
        double u = (double)i / (double)(TT - 1) - 0.5;
        double u2 = u * u;
        S2 += u2;
        S4 += u2 * u2;
    }
    const double c20d = S2 / S0;
    const double Dd = S4 - S2 * S2 / S0;
    const float scale = (float)(1.0 / (double)(TT - 1));
    const float invS0 = (float)(1.0 / S0);
    const float invS2 = (float)(1.0 / S2);
    const float invD  = (float)(1.0 / Dd);
    const float c20   = (float)c20d;

    const size_t partial_elems = (size_t)BB * NGM * 3 * C4;   // f4 units
    const size_t need_bytes    = partial_elems * sizeof(f4);  // 768 KB

    if (ws_size >= need_bytes) {
        f4* partial = (f4*)d_ws;
        k_moments_zero<<<BB * NGM + BB * NTILE, 256, 0, stream>>>(
            (const f4*)x, partial, (f4*)out, scale);
        k_emit<<<BB * NTILE, 256, 0, stream>>>(
            (const f4*)x, partial, (f4*)out, scale, c20, invS0, invS2, invD);
    } else {
        // Fallback: partials in zero-plane 2; final memset wipes scratch and
        // produces both zero planes.
        f4* partial = (f4*)(out + 2 * N);
        k_moments_zero<<<BB * NGM, 256, 0, stream>>>(
            (const f4*)x, partial, (f4*)out, scale);
        k_emit<<<BB * NTILE, 256, 0, stream>>>(
            (const f4*)x, partial, (f4*)out, scale, c20, invS0, invS2, invD);
        hipMemsetAsync(out + 2 * N, 0, 2 * N * sizeof(float), stream);
    }
}

// Round 11
// 61.689 us; speedup vs baseline: 1.0210x; 1.0210x over previous
//
#include <hip/hip_runtime.h>
#include <hip/hip_cooperative_groups.h>

namespace cg = cooperative_groups;

typedef float f4 __attribute__((ext_vector_type(4)));

#define TT 4096
#define CC 128
#define BB 32
#define C4 (CC / 4)        // 32 float4 per row
#define NB 1024            // cooperative grid: 32 blocks per batch
#define ROWS_B 128         // rows per block
#define RECS 32            // partial records per batch

// ---------------------------------------------------------------------------
// Single-pass fused cooperative kernel — x read EXACTLY once:
//   Phase 1: load x tile into REGISTERS (xv[16]), accumulate moments,
//            interleave zero-plane writes (128 MB W mixed with 64 MB R).
//   grid.sync
//   Phase 2: reduce 32 partial records -> coefficients (L2-resident).
//   Phase 3: emit low/res from the register-resident tile (no re-read).
// 1024 blocks x 256 thr; __launch_bounds__(256,4) caps VGPR at 128 so
// 4 blocks/CU stay co-resident (required for the cooperative launch).
// ---------------------------------------------------------------------------
__global__ __launch_bounds__(256, 4) void k_fused(const f4* __restrict__ x4,
                                                  f4* __restrict__ partial,
                                                  f4* __restrict__ out,
                                                  float scale, float c20,
                                                  float invS0, float invS2,
                                                  float invD) {
    const size_t N4 = (size_t)BB * TT * C4;   // one output plane, f4 units
    const int blk = blockIdx.x;
    const int b = blk >> 5;      // 32 blocks per batch
    const int tile = blk & 31;   // which 128-row tile
    const int tid = threadIdx.x;
    const int r = tid >> 5;      // 0..7
    const int q = tid & 31;      // 0..31

    __shared__ f4 red[3][8][32];
    __shared__ f4 ca[3][32];

    const size_t base = (size_t)b * TT * C4;
    const int t0 = tile * ROWS_B;
    const f4 z = (f4)0.0f;

    // ---- Phase 1: single read of x into registers + moments + zero writes --
    f4 xv[16];
    f4 m0 = (f4)0.0f, m1 = (f4)0.0f, m2 = (f4)0.0f;
#pragma unroll
    for (int k = 0; k < 16; ++k) {
        const int t = t0 + r + (k << 3);
        const float u = fmaf((float)t, scale, -0.5f);
        const size_t idx = base + (size_t)t * C4 + q;
        xv[k] = x4[idx];
        m0 += xv[k];
        m1 += u * xv[k];
        m2 += (u * u) * xv[k];
        __builtin_nontemporal_store(z, &out[2 * N4 + idx]);
        __builtin_nontemporal_store(z, &out[3 * N4 + idx]);
    }
    red[0][r][q] = m0;
    red[1][r][q] = m1;
    red[2][r][q] = m2;
    __syncthreads();
    if (tid < 32) {
#pragma unroll
        for (int j = 0; j < 3; ++j) {
            f4 acc = red[j][0][tid];
#pragma unroll
            for (int rr = 1; rr < 8; ++rr) acc += red[j][rr][tid];
            partial[(size_t)blk * (3 * C4) + j * C4 + tid] = acc;
        }
    }

    // ---- grid-wide barrier (device-scope fence: partials visible) ----
    cg::this_grid().sync();

    // ---- Phase 2: reduce this batch's 32 records ----
    const f4* pb = partial + (size_t)b * (RECS * 3 * C4);
#pragma unroll
    for (int j = 0; j < 3; ++j) {
        f4 acc = (f4)0.0f;
#pragma unroll
        for (int k = 0; k < 4; ++k)
            acc += pb[(size_t)(4 * r + k) * (3 * C4) + j * C4 + q];
        red[j][r][q] = acc;
    }
    __syncthreads();
    if (tid < 32) {
        f4 s0 = (f4)0.0f, s1 = (f4)0.0f, s2 = (f4)0.0f;
#pragma unroll
        for (int rr = 0; rr < 8; ++rr) {
            s0 += red[0][rr][tid];
            s1 += red[1][rr][tid];
            s2 += red[2][rr][tid];
        }
        ca[0][tid] = s0 * invS0;
        ca[1][tid] = s1 * invS2;
        ca[2][tid] = (s2 - c20 * s0) * invD;
    }
    __syncthreads();

    const f4 a0 = ca[0][q];
    const f4 a1 = ca[1][q];
    const f4 a2 = ca[2][q];

    // ---- Phase 3: emit low/res from registers (x never re-read) ----
#pragma unroll
    for (int k = 0; k < 16; ++k) {
        const int t = t0 + r + (k << 3);
        const float u = fmaf((float)t, scale, -0.5f);
        const float w = fmaf(u, u, -c20);
        const size_t idx = base + (size_t)t * C4 + q;
        const f4 lo = a0 + u * a1 + w * a2;
        const f4 re = xv[k] - lo;
        __builtin_nontemporal_store(lo, &out[idx]);
        __builtin_nontemporal_store(re, &out[N4 + idx]);
    }
}

// ===========================================================================
// Fallback path (R4 structure, measured 61.7 us): two kernels.
// ===========================================================================
#define NGM 16
#define SLAB (TT / NGM)
#define NTILE 64

__global__ __launch_bounds__(256) void k_moments_zero(const f4* __restrict__ x4,
                                                      f4* __restrict__ partial,
                                                      f4* __restrict__ out,
                                                      float scale) {
    const size_t N4 = (size_t)BB * TT * C4;
    const int blk = blockIdx.x;
    const int tid = threadIdx.x;
    const int r = tid >> 5;
    const int q = tid & 31;

    if (blk < BB * NGM) {
        const int b = blk >> 4;
        const int s = blk & 15;
        const f4* xb = x4 + (size_t)b * TT * C4;
        const int t0 = s * SLAB;
        f4 m0 = (f4)0.0f, m1 = (f4)0.0f, m2 = (f4)0.0f;
#pragma unroll 8
        for (int k = 0; k < SLAB / 8; ++k) {
            const int t = t0 + r + (k << 3);
            const float u = fmaf((float)t, scale, -0.5f);
            const f4 v = xb[(size_t)t * C4 + q];
            m0 += v;
            m1 += u * v;
            m2 += (u * u) * v;
        }
        __shared__ f4 red[3][8][32];
        red[0][r][q] = m0;
        red[1][r][q] = m1;
        red[2][r][q] = m2;
        __syncthreads();
        if (tid < 32) {
#pragma unroll
            for (int j = 0; j < 3; ++j) {
                f4 acc = red[j][0][tid];
#pragma unroll
                for (int rr = 1; rr < 8; ++rr) acc += red[j][rr][tid];
                partial[(size_t)blk * (3 * C4) + j * C4 + tid] = acc;
            }
        }
    } else {
        const int zid = blk - BB * NGM;
        const int b = zid >> 6;
        const int tile = zid & 63;
        const size_t base = (size_t)b * TT * C4 + (size_t)(tile * 64) * C4;
        const f4 z = (f4)0.0f;
#pragma unroll
        for (int k = 0; k < 8; ++k) {
            const size_t idx = base + (size_t)(r + (k << 3)) * C4 + q;
            __builtin_nontemporal_store(z, &out[2 * N4 + idx]);
            __builtin_nontemporal_store(z, &out[3 * N4 + idx]);
        }
    }
}

__global__ __launch_bounds__(256) void k_emit(const f4* __restrict__ x4,
                                              const f4* __restrict__ partial,
                                              f4* __restrict__ out,
                                              float scale, float c20,
                                              float invS0, float invS2,
                                              float invD) {
    const size_t N4 = (size_t)BB * TT * C4;
    const int blk = blockIdx.x;
    const int b = blk >> 6;
    const int tile = blk & 63;
    const int tid = threadIdx.x;
    const int r = tid >> 5;
    const int q = tid & 31;

    __shared__ f4 red[3][8][32];
    __shared__ f4 ca[3][32];

    const f4* pb = partial + (size_t)b * (NGM * 3 * C4);
#pragma unroll
    for (int j = 0; j < 3; ++j) {
        const f4 e0 = pb[(size_t)(2 * r + 0) * (3 * C4) + j * C4 + q];
        const f4 e1 = pb[(size_t)(2 * r + 1) * (3 * C4) + j * C4 + q];
        red[j][r][q] = e0 + e1;
    }
    __syncthreads();
    if (tid < 32) {
        f4 s0 = (f4)0.0f, s1 = (f4)0.0f, s2 = (f4)0.0f;
#pragma unroll
        for (int rr = 0; rr < 8; ++rr) {
            s0 += red[0][rr][tid];
            s1 += red[1][rr][tid];
            s2 += red[2][rr][tid];
        }
        ca[0][tid] = s0 * invS0;
        ca[1][tid] = s1 * invS2;
        ca[2][tid] = (s2 - c20 * s0) * invD;
    }
    __syncthreads();

    const f4 a0 = ca[0][q];
    const f4 a1 = ca[1][q];
    const f4 a2 = ca[2][q];

    const size_t base = (size_t)b * TT * C4;
    const int t0 = tile * 64;
#pragma unroll
    for (int k = 0; k < 8; ++k) {
        const int t = t0 + r + (k << 3);
        const float u = fmaf((float)t, scale, -0.5f);
        const float w = fmaf(u, u, -c20);
        const size_t idx = base + (size_t)t * C4 + q;
        const f4 xv = x4[idx];
        const f4 lo = a0 + u * a1 + w * a2;
        const f4 re = xv - lo;
        __builtin_nontemporal_store(lo, &out[idx]);
        __builtin_nontemporal_store(re, &out[N4 + idx]);
    }
}

// ---------------------------------------------------------------------------
extern "C" void kernel_launch(void* const* d_in, const int* in_sizes, int n_in,
                              void* d_out, int out_size, void* d_ws, size_t ws_size,
                              hipStream_t stream) {
    const float* x = (const float*)d_in[0];
    float* out = (float*)d_out;
    const size_t N = (size_t)BB * TT * CC;

    // Exact basis scalars in double on host (t symmetric => S1 = S3 = 0).
    double S0 = (double)TT, S2 = 0.0, S4 = 0.0;
    for (int i = 0; i < TT; ++i) {
        double u = (double)i / (double)(TT - 1) - 0.5;
        double u2 = u * u;
        S2 += u2;
        S4 += u2 * u2;
    }
    const double c20d = S2 / S0;
    const double Dd = S4 - S2 * S2 / S0;
    float scale = (float)(1.0 / (double)(TT - 1));
    float invS0 = (float)(1.0 / S0);
    float invS2 = (float)(1.0 / S2);
    float invD  = (float)(1.0 / Dd);
    float c20   = (float)c20d;

    const size_t coop_need = (size_t)NB * 3 * C4 * sizeof(f4);   // 1.5 MB

    // --- Single-pass cooperative path (x read once, register-resident) ---
    if (ws_size >= coop_need) {
        int dev = 0, coop = 0, cus = 0, occ = 0;
        if (hipGetDevice(&dev) == hipSuccess &&
            hipDeviceGetAttribute(&coop, hipDeviceAttributeCooperativeLaunch,
                                  dev) == hipSuccess &&
            coop &&
            hipDeviceGetAttribute(&cus, hipDeviceAttributeMultiprocessorCount,
                                  dev) == hipSuccess &&
            hipOccupancyMaxActiveBlocksPerMultiprocessor(
                &occ, (const void*)k_fused, 256, 0) == hipSuccess &&
            occ * cus >= NB) {
            const f4* x4 = (const f4*)x;
            f4* partial = (f4*)d_ws;
            f4* out4 = (f4*)out;
            void* args[] = {(void*)&x4, (void*)&partial, (void*)&out4,
                            (void*)&scale, (void*)&c20,
                            (void*)&invS0, (void*)&invS2, (void*)&invD};
            hipError_t err = hipLaunchCooperativeKernel(
                (const void*)k_fused, dim3(NB), dim3(256), args, 0, stream);
            if (err == hipSuccess) return;
        }
    }

    // --- Fallback: proven two-kernel path (R4, 61.7 us) ---
    const size_t fb_need = (size_t)BB * NGM * 3 * C4 * sizeof(f4);
    if (ws_size >= fb_need) {
        f4* partial = (f4*)d_ws;
        k_moments_zero<<<BB * NGM + BB * NTILE, 256, 0, stream>>>(
            (const f4*)x, partial, (f4*)out, scale);
        k_emit<<<BB * NTILE, 256, 0, stream>>>(
            (const f4*)x, partial, (f4*)out, scale, c20, invS0, invS2, invD);
    } else {
        f4* partial = (f4*)(out + 2 * N);
        k_moments_zero<<<BB * NGM, 256, 0, stream>>>(
            (const f4*)x, partial, (f4*)out, scale);
        k_emit<<<BB * NTILE, 256, 0, stream>>>(
            (const f4*)x, partial, (f4*)out, scale, c20, invS0, invS2, invD);
        hipMemsetAsync(out + 2 * N, 0, 2 * N * sizeof(float), stream);
    }
}